// Round 13
// baseline (42.932 us; speedup 1.0000x reference)
//
#include <hip/hip_runtime.h>
#include <hip/hip_bf16.h>
#include <stdint.h>

// GPTQ 4-bit fused dequant + GEMM.  x[128,4096]f32 @ W[4096,11008] -> out[128,11008]f32
// W[k][n] = scales[k/128][n] * nibble(qweight[k/8][n], k%8) - zeros[k/128][n]
//
// R13 = R12 (zero-LDS, frag-major A, deq8i 128+q exact, running rescale,
//       WM=64, SPLIT=4, 688x256) + A-PREFETCH 1-DEEP:
//   vmcnt retires in issue order; R12 loaded A in the consuming iteration, so
//   the MFMA's A-wait transitively waited on prev-iter q-loads (age ~400cyc of
//   a 900cyc HBM latency) -> ~500cyc/iter structural stall. Now A(cc+1) is
//   issued at top of iter cc (BEFORE q(cc+3)): at MFMA(cc), A is 1 iter old and
//   all older q-loads are ~2 iters old (~retired) -> stall ~100cyc.
//   VGPR budget (cliff at 128): acc32 + aP64 + qP12 + sv8 + addr ~= 125.
//   rr[] dropped (boundary ratio recomputed by divide); cg/zeros epilogue-only.

#define IN_F   4096
#define OUT_F  11008
#define BATCH  128
#define SPLIT  4
#define KSLICE (IN_F / SPLIT)   // 1024
#define KSC    (KSLICE / 64)    // 16 chunks per slice
#define NCHG   (IN_F / 64)      // 64 global chunks
#define NBN    86               // n-blocks (128 cols each)
#define NBLK   (NBN * 2 * SPLIT)// 688
#define MN     (BATCH * OUT_F)  // 1409024
#define NGRP   (IN_F / 128)     // 32 groups

typedef __attribute__((ext_vector_type(8)))  short short8;
typedef __attribute__((ext_vector_type(16))) float f32x16;

static __device__ __forceinline__ unsigned int f2bf_pack(float lo, float hi) {
  unsigned int a = __float_as_uint(lo);
  unsigned int b = __float_as_uint(hi);
  a += 0x7FFFu + ((a >> 16) & 1u);
  b += 0x7FFFu + ((b >> 16) & 1u);
  return (a >> 16) | (b & 0xFFFF0000u);
}

static __device__ __forceinline__ float bf16_round_f32(float v) {
  unsigned int u = __float_as_uint(v);
  u += 0x7FFFu + ((u >> 16) & 1u);
  return __uint_as_float(u & 0xFFFF0000u);
}

// x[128][4096] f32 -> xs frag-major bf16 (16B unit = ((mt*64+cg)*4+ks)*64+lane,
// lane = hi*32+lo32, holding x[mt*32+lo32][cg*64+ks*16+hi*8 + 0..7])
// + rsum[128][32]: per-(row, group) sum of the bf16-ROUNDED x values.
__global__ __launch_bounds__(256) void cvt_swz(const float* __restrict__ x,
                                               uint4* __restrict__ xs,
                                               float* __restrict__ rsum) {
  int t  = blockIdx.x * 256 + threadIdx.x;   // 65536 threads
  int m  = t >> 9;                           // 0..127
  int k  = (t & 511) * 8;                    // 0..4088, step 8
  float4 u0 = *(const float4*)(x + (size_t)m * IN_F + k);
  float4 u1 = *(const float4*)(x + (size_t)m * IN_F + k + 4);
  uint4 o;
  o.x = f2bf_pack(u0.x, u0.y);
  o.y = f2bf_pack(u0.z, u0.w);
  o.z = f2bf_pack(u1.x, u1.y);
  o.w = f2bf_pack(u1.z, u1.w);
  int mt = m >> 5, lo32 = m & 31;
  int cg = k >> 6, ks = (k >> 4) & 3, hi = (k >> 3) & 1;
  size_t idx = (size_t)(((mt * NCHG + cg) * 4 + ks) << 6) + hi * 32 + lo32;
  xs[idx] = o;

  float s8 = bf16_round_f32(u0.x) + bf16_round_f32(u0.y) +
             bf16_round_f32(u0.z) + bf16_round_f32(u0.w) +
             bf16_round_f32(u1.x) + bf16_round_f32(u1.y) +
             bf16_round_f32(u1.z) + bf16_round_f32(u1.w);
  s8 += __shfl_xor(s8, 1, 16);
  s8 += __shfl_xor(s8, 2, 16);
  s8 += __shfl_xor(s8, 4, 16);
  s8 += __shfl_xor(s8, 8, 16);
  if ((t & 15) == 0) {
    int g = (t & 511) >> 4;                  // 0..31
    rsum[m * NGRP + g] = s8;
  }
}

__global__ __launch_bounds__(256) void zero_out(float* __restrict__ out) {
  int base = (blockIdx.x * 256 + threadIdx.x) * 16;   // 344 blocks
  float4 z = {0.f, 0.f, 0.f, 0.f};
#pragma unroll
  for (int j = 0; j < 4; ++j) *(float4*)(out + base + j * 4) = z;
}

__global__ __launch_bounds__(256) void reduce_kernel(const float* __restrict__ part,
                                                     float* __restrict__ out) {
  int base = (blockIdx.x * 256 + threadIdx.x) * 8;    // 688 blocks
  float4 s0 = {0.f, 0.f, 0.f, 0.f}, s1 = s0;
#pragma unroll
  for (int s = 0; s < SPLIT; ++s) {
    const float* p = part + (size_t)s * MN + base;
    float4 a = *(const float4*)(p);
    float4 b = *(const float4*)(p + 4);
    s0.x += a.x; s0.y += a.y; s0.z += a.z; s0.w += a.w;
    s1.x += b.x; s1.y += b.y; s1.z += b.z; s1.w += b.w;
  }
  *(float4*)(out + base)     = s0;
  *(float4*)(out + base + 4) = s1;
}

// dequant one packed int32 into bf16 (128 + q) -- pure bit ops, EXACT
static __device__ __forceinline__ short8 deq8i(unsigned int q) {
  union { unsigned int u[4]; short8 s8; } r;
#pragma unroll
  for (int j = 0; j < 4; ++j)
    r.u[j] = 0x43004300u | ((q >> (8 * j)) & 0xFu) |
             (((q >> (8 * j + 4)) & 0xFu) << 16);
  return r.s8;
}

// load 4 q-words (one chunk's B data for this lane) into prefetch set S
#define LOAD_Q(S, CC) do {                                                     \
    _Pragma("unroll")                                                          \
    for (int ks_ = 0; ks_ < 4; ++ks_)                                          \
      qP[S][ks_] = qlane[(size_t)((CC) * 8 + ks_ * 2) * OUT_F];                \
  } while (0)

// load one chunk's A fragments (both 32-row halves) into prefetch set S
#define LOAD_A(S, CC) do {                                                     \
    _Pragma("unroll")                                                          \
    for (int ks_ = 0; ks_ < 4; ++ks_) {                                        \
      aP[S][0][ks_] = aB0[(size_t)((CC) * 4 + ks_) << 6];                      \
      aP[S][1][ks_] = aB1[(size_t)((CC) * 4 + ks_) << 6];                      \
    }                                                                          \
  } while (0)

__global__ __launch_bounds__(256) void gptq_gemm(
    const uint4* __restrict__ xs,           // frag-major x (bf16)
    const int* __restrict__ qweight,        // [512, 11008]
    const float* __restrict__ scales,       // [32, 11008]
    const float* __restrict__ zeros,        // [32, 11008]
    const float* __restrict__ rsum,         // [128, 32]
    float* __restrict__ outp,               // out (atomic) or partials base
    int atomic_mode) {
  const int tid  = threadIdx.x;
  const int lane = tid & 63;
  const int wid  = tid >> 6;
  const int hi   = lane >> 5;          // 0/1: k-half within fragment
  const int lo32 = lane & 31;

  const int nb = blockIdx.x % NBN;
  const int mb = (blockIdx.x / NBN) & 1;
  const int sl = blockIdx.x / (NBN * 2);

  const int ncol = nb * 128 + wid * 32 + lo32;  // this lane's output column
  const int m0   = mb * 64;                     // rows m0..m0+63

  float* dst = atomic_mode ? outp : outp + (size_t)sl * MN;

  // scales for this slice's 8 groups (ratios recomputed at boundaries)
  float sv[8];
#pragma unroll
  for (int g = 0; g < 8; ++g)
    sv[g] = scales[(size_t)(sl * 8 + g) * OUT_F + ncol];

  const int* qlane = qweight + (size_t)(sl * (KSLICE / 8) + hi) * OUT_F + ncol;
  const uint4* aB0 = xs + ((size_t)((mb * 2 + 0) * NCHG + sl * KSC) << 8) + lane;
  const uint4* aB1 = xs + ((size_t)((mb * 2 + 1) * NCHG + sl * KSC) << 8) + lane;

  uint4 aP[2][2][4];
  unsigned int qP[3][4];

  // prologue: A for chunk 0 FIRST (oldest in queue), then q 3-deep
  LOAD_A(0, 0);
  LOAD_Q(0, 0);
  LOAD_Q(1, 1);
  LOAD_Q(2, 2);

  f32x16 acc[2] = {};

#pragma unroll
  for (int cc = 0; cc < KSC; ++cc) {
    const int cur = cc & 1;

    // issue next chunk's A loads FIRST (A stays older than all newer q)
    if (cc + 1 < KSC) LOAD_A(cur ^ 1, cc + 1);

    // dequant chunk cc's q-words (loaded 3 iters ago -> retired)
    short8 bF[4];
#pragma unroll
    for (int ks = 0; ks < 4; ++ks)
      bF[ks] = deq8i(qP[cc % 3][ks]);

    // refill the just-freed q set (issued after this iter's A)
    if (cc + 3 < KSC) LOAD_Q(cc % 3, cc + 3);

    // 8 MFMAs on the 1-iter-old A set
#pragma unroll
    for (int ks = 0; ks < 4; ++ks) {
      union { uint4 u; short8 s8; } a0, a1;
      a0.u = aP[cur][0][ks];
      a1.u = aP[cur][1][ks];
      acc[0] = __builtin_amdgcn_mfma_f32_32x32x16_bf16(a0.s8, bF[ks], acc[0], 0, 0, 0);
      acc[1] = __builtin_amdgcn_mfma_f32_32x32x16_bf16(a1.s8, bF[ks], acc[1], 0, 0, 0);
    }

    // group boundary (group = 2 chunks): acc *= s_g / s_{g+1}
    if ((cc & 1) && cc != KSC - 1) {
      const float r = sv[cc >> 1] / sv[(cc >> 1) + 1];
#pragma unroll
      for (int j = 0; j < 16; ++j) {
        acc[0][j] *= r;
        acc[1][j] *= r;
      }
    }
  }

  // epilogue: val = s_last * acc - sum_g (128 s_g + z_g) rsum_g[row]
  float cg[8];
#pragma unroll
  for (int g = 0; g < 8; ++g)
    cg[g] = 128.f * sv[g] + zeros[(size_t)(sl * 8 + g) * OUT_F + ncol];
  const float slast = sv[7];

#pragma unroll
  for (int mi = 0; mi < 2; ++mi) {
#pragma unroll
    for (int reg = 0; reg < 16; ++reg) {
      int row = m0 + mi * 32 + 4 * hi + (reg & 3) + 8 * (reg >> 2);
      const float4* rp = (const float4*)(rsum + (size_t)row * NGRP + sl * 8);
      float4 r0 = rp[0], r1 = rp[1];
      float corr = cg[0] * r0.x + cg[1] * r0.y + cg[2] * r0.z + cg[3] * r0.w +
                   cg[4] * r1.x + cg[5] * r1.y + cg[6] * r1.z + cg[7] * r1.w;
      float val = slast * acc[mi][reg] - corr;
      if (atomic_mode) {
        atomicAdd(dst + (size_t)row * OUT_F + ncol, val);
      } else {
        dst[(size_t)row * OUT_F + ncol] = val;
      }
    }
  }
}

extern "C" void kernel_launch(void* const* d_in, const int* in_sizes, int n_in,
                              void* d_out, int out_size, void* d_ws, size_t ws_size,
                              hipStream_t stream) {
  const float* x       = (const float*)d_in[0];
  const int*   qweight = (const int*)d_in[1];
  const float* scales  = (const float*)d_in[2];
  const float* zeros   = (const float*)d_in[3];
  float*       outp    = (float*)d_out;

  const size_t xs_bytes   = (size_t)BATCH * IN_F * sizeof(unsigned short);  // 1 MB
  const size_t rs_bytes   = (size_t)BATCH * NGRP * sizeof(float);           // 16 KB
  const size_t part_bytes = (size_t)SPLIT * MN * sizeof(float);             // 22.5 MB
  int partials = (ws_size >= xs_bytes + rs_bytes + part_bytes) ? 1 : 0;

  uint4* xs   = (uint4*)d_ws;
  float* rsum = (float*)((char*)d_ws + xs_bytes);
  float* part = (float*)((char*)d_ws + xs_bytes + rs_bytes);

  cvt_swz<<<256, 256, 0, stream>>>(x, xs, rsum);

  if (partials) {
    gptq_gemm<<<NBLK, 256, 0, stream>>>(xs, qweight, scales, zeros, rsum, part, 0);
    reduce_kernel<<<688, 256, 0, stream>>>(part, outp);
  } else {
    zero_out<<<344, 256, 0, stream>>>(outp);
    gptq_gemm<<<NBLK, 256, 0, stream>>>(xs, qweight, scales, zeros, rsum, outp, 1);
  }
}